// Round 10
// baseline (7758.722 us; speedup 1.0000x reference)
//
#include <hip/hip_runtime.h>
#include <hip/hip_bf16.h>

#define B_ 32
#define T_ 512
#define D_ 1024
#define N_ 1024
#define NWG 192
#define NGATE 128
#define TPB 128
// LDS: weights [2][64][64][8] ushort = 131072 + bias 64  (no reduce buffer!)
#define SMEM_BYTES (131072 + 64)

typedef __attribute__((ext_vector_type(8))) short short8v;
typedef __attribute__((ext_vector_type(4))) float f32x4;

__device__ __forceinline__ float bf2f(unsigned short u) {
  union { float f; unsigned int i; } c; c.i = ((unsigned int)u) << 16; return c.f;
}
__device__ __forceinline__ unsigned short f2bf(float f) {   // software RNE (scalar)
  union { float f; unsigned int i; } c; c.f = f;
  unsigned int r = c.i + 0x7FFFu + ((c.i >> 16) & 1u);
  return (unsigned short)(r >> 16);
}
// HW packed f32->bf16 RNE (bulk activation conversions)
__device__ __forceinline__ unsigned cvtpk(float a, float b) {
  unsigned r;
  asm("v_cvt_pk_bf16_f32 %0, %1, %2" : "=v"(r) : "v"(a), "v"(b));
  return r;
}
__device__ __forceinline__ short8v pack_frag(f32x4 lo, f32x4 hi) {
  union { unsigned u[4]; short8v s; } c;
  c.u[0] = cvtpk(lo[0], lo[1]); c.u[1] = cvtpk(lo[2], lo[3]);
  c.u[2] = cvtpk(hi[0], hi[1]); c.u[3] = cvtpk(hi[2], hi[3]);
  return c.s;
}

// ---- direct-to-LLC accessors (bypass L1+L2): all cross-WG data.
__device__ __forceinline__ void st_bf16_sc(unsigned short* p, unsigned short v) {
  asm volatile("global_store_short %0, %1, off sc0 sc1"
               :: "v"((unsigned long long)p), "v"((unsigned)v) : "memory");
}
__device__ __forceinline__ void st_f32_sc(float* p, float v) {
  asm volatile("global_store_dword %0, %1, off sc0 sc1"
               :: "v"((unsigned long long)p), "v"(v) : "memory");
}

// ---- per-WAVE epoch flags (single writer per 64B line, monotonic).
// Writer wave: [data sc1 stores] -> wave vmcnt(0) -> lane0 relaxed agent store.
// Reader: relaxed agent poll -> sc1 data loads. (Protocol proven R3/R6-R9.)
__device__ __forceinline__ void flag_store(unsigned* line, unsigned v) {
  __hip_atomic_store(line, v, __ATOMIC_RELAXED, __HIP_MEMORY_SCOPE_AGENT);
}
__device__ __forceinline__ void poll2(const unsigned* p0, bool a0,
                                      const unsigned* p1, bool a1, unsigned tgt) {
  int tries = 0;
  for (;;) {
    unsigned v0 = tgt, v1 = tgt;
    if (a0) v0 = __hip_atomic_load(p0, __ATOMIC_RELAXED, __HIP_MEMORY_SCOPE_AGENT);
    if (a1) v1 = __hip_atomic_load(p1, __ATOMIC_RELAXED, __HIP_MEMORY_SCOPE_AGENT);
    if (__all((int)(v0 >= tgt && v1 >= tgt))) break;
    __builtin_amdgcn_s_sleep(1);
    if (++tries > (1 << 20)) break;   // deadlock valve; never hit normally
  }
}

// Fragment-order flat offset for [32 rows][1024 k] bf16 stored [mt][ks][lane][8].
__device__ __forceinline__ int frag_off(int m, int k) {
  const int mt = m >> 4, ks = k >> 5, kk = k & 31;
  const int l = (m & 15) + (((kk >> 2) & 3) << 4);
  const int j = (kk & 3) + ((kk >> 4) << 2);
  return ((mt * 32 + ks) * 64 + l) * 8 + j;
}

// Shadow x-part: full K=1024 for this wave's m-tile, accumulated into acc[0..3]
// (acc split: [hi/lo] x [ks<16 / ks>=16] for MFMA ILP). Plain cached loads.
__device__ __forceinline__ void shadow_x(const float* __restrict__ x, int t,
                                         int m16, int lane,
                                         const unsigned short* __restrict__ ldsW,
                                         f32x4* acc) {
  const float* row = x + ((size_t)(m16 + (lane & 15)) * T_ + t) * D_;
#pragma unroll
  for (int c = 0; c < 4; ++c) {
    short8v xf[8];
#pragma unroll
    for (int i = 0; i < 8; ++i) {
      const int ks = c * 8 + i;
      const int k0 = ks * 32 + ((lane >> 4) << 2);
      f32x4 lo = *(const f32x4*)(row + k0);
      f32x4 hi = *(const f32x4*)(row + k0 + 16);
      xf[i] = pack_frag(lo, hi);
    }
#pragma unroll
    for (int i = 0; i < 8; ++i) {
      const int ks = c * 8 + i;
      short8v bhi = *(const short8v*)(ldsW + ((size_t)(0 * 64 + ks) * 64 + lane) * 8);
      short8v blo = *(const short8v*)(ldsW + ((size_t)(1 * 64 + ks) * 64 + lane) * 8);
      const int a = (ks & 16) ? 2 : 0;
      acc[a]     = __builtin_amdgcn_mfma_f32_16x16x32_bf16(xf[i], bhi, acc[a], 0, 0, 0);
      acc[a + 1] = __builtin_amdgcn_mfma_f32_16x16x32_bf16(xf[i], blo, acc[a + 1], 0, 0, 0);
    }
  }
}

__global__ __launch_bounds__(TPB, 1) void gru_persistent(
    const float* __restrict__ x, const float* __restrict__ h0,
    const float* __restrict__ Wg, const float* __restrict__ bg,
    const float* __restrict__ Wc, const float* __restrict__ bc,
    float* __restrict__ out,
    unsigned* __restrict__ ctrs,
    unsigned short* __restrict__ hq,     // [2 parity][frag 32x1024] bf16 h
    unsigned short* __restrict__ rhq,    // [frag 32x1024] bf16 r*h
    float* __restrict__ u_buf,           // [32][1024] f32 u gate
    float* __restrict__ h_buf)           // [32][1024] f32 h (row-major)
{
  const int wg = blockIdx.x;
  const int tid = threadIdx.x;
  const int lane = tid & 63;
  const int wv = tid >> 6;               // 0/1: batch-half pipeline (rows wv*16..)

  extern __shared__ char smem[];
  unsigned short* ldsW = (unsigned short*)smem;            // [2][64][64][8]
  float* ldsBias = (float*)(smem + 131072);                // [16]

  unsigned* flagH = ctrs;                  // 128 lines: (cand cidx, wave)
  unsigned* flagG = ctrs + 128 * 16;       // 256 lines: (gate wg, wave)

  const bool is_gate = wg < NGATE;
  const int c0 = (is_gate ? wg : (wg - NGATE)) * 16;
  const float* Wsrc = is_gate ? Wg : Wc;
  const int ldw = is_gate ? 2 * N_ : N_;
  const float* bias = is_gate ? bg : bc;

  const int colg = c0 + (lane & 15);
  const int r0 = wv * 16 + ((lane >> 4) << 2);   // first of this lane's 4 rows

  // ---- preload weight slice into LDS in MFMA-fragment order, hi/lo split bf16
  for (int i = tid; i < 64 * 64; i += TPB) {
    const int ks = i >> 6, l = i & 63;
    const int n = l & 15, kqp = (l >> 4) * 4;
#pragma unroll
    for (int j = 0; j < 8; ++j) {
      const int k = ks * 32 + ((j < 4) ? 0 : 16) + kqp + (j & 3);
      const float w = Wsrc[(size_t)k * ldw + c0 + n];
      const unsigned short hi = f2bf(w);
      const unsigned short lo = f2bf(w - bf2f(hi));
      ldsW[((size_t)(0 * 64 + ks) * 64 + l) * 8 + j] = hi;
      ldsW[((size_t)(1 * 64 + ks) * 64 + l) * 8 + j] = lo;
    }
  }
  if (tid < 16) ldsBias[tid] = bias[c0 + tid];
  __syncthreads();   // the ONLY barrier: waves are fully independent after this

  if (is_gate) {
    const bool r_wg = (c0 < N_);
    unsigned* wflag = flagG + (size_t)(wg * 2 + wv) * 16;
    // lane l polls cand WG l, wave wv (its h granule producers: diagonal mt)
    const unsigned* pp = flagH + (size_t)(lane * 2 + wv) * 16;
    // r-WG extra: cand WG 'wg' wave wv produced the h_buf scalars this wave reads
    const unsigned* pe = flagH + (size_t)(wg * 2 + wv) * 16;
    const bool ae = r_wg && (lane == 0);

    f32x4 acc[4] = {{0,0,0,0},{0,0,0,0},{0,0,0,0},{0,0,0,0}};
    shadow_x(x, 0, wv * 16, lane, ldsW, acc);    // x0 @ Wg_x (shadow)

    for (int t = 0; t < T_; ++t) {
      poll2(pp, true, pe, ae, (unsigned)(t + 1));
      const unsigned short* hqr = hq + (((t + 1) & 1) << 15);  // h(t-1) parity
      // ---- one issue-batch: (r-WG) 4 h scalars + 32 hq granules
      float hv[4];
      if (r_wg) {
#pragma unroll
        for (int r = 0; r < 4; ++r)
          asm volatile("global_load_dword %0, %1, off sc0 sc1"
                       : "=v"(hv[r])
                       : "v"((unsigned long long)(h_buf + (size_t)(r0 + r) * N_ + colg))
                       : "memory");
      }
      short8v areg[32];
#pragma unroll
      for (int ks = 0; ks < 32; ++ks) {
        const unsigned short* p = hqr + ((size_t)((wv * 32 + ks) * 64 + lane)) * 8;
        asm volatile("global_load_dwordx4 %0, %1, off sc0 sc1"
                     : "=v"(areg[ks]) : "v"((unsigned long long)p) : "memory");
      }
      asm volatile("s_waitcnt vmcnt(0)" ::: "memory");
      __builtin_amdgcn_sched_barrier(0);         // rule #18
#pragma unroll
      for (int ks = 0; ks < 32; ++ks) {
        const int ksg = 32 + ks;                 // h-part weights
        short8v bhi = *(const short8v*)(ldsW + ((size_t)(0 * 64 + ksg) * 64 + lane) * 8);
        short8v blo = *(const short8v*)(ldsW + ((size_t)(1 * 64 + ksg) * 64 + lane) * 8);
        const int a = (ks & 16) ? 2 : 0;
        acc[a]     = __builtin_amdgcn_mfma_f32_16x16x32_bf16(areg[ks], bhi, acc[a], 0, 0, 0);
        acc[a + 1] = __builtin_amdgcn_mfma_f32_16x16x32_bf16(areg[ks], blo, acc[a + 1], 0, 0, 0);
      }
      // ---- epilogue: merge 4 acc chains, nonlinearity, protocol stores
      f32x4 s4 = (acc[0] + acc[1]) + (acc[2] + acc[3]);
      const float bcol = ldsBias[lane & 15];
#pragma unroll
      for (int r = 0; r < 4; ++r) {
        float pre = fminf(fmaxf(s4[r] + bcol, -30.f), 30.f);
        const float g = 1.f / (1.f + __expf(-pre));
        if (r_wg) st_bf16_sc(rhq + frag_off(r0 + r, colg), f2bf(g * hv[r]));
        else      st_f32_sc(u_buf + (size_t)(r0 + r) * N_ + (colg - N_), g);
      }
      asm volatile("s_waitcnt vmcnt(0)" ::: "memory");  // wave-local drain
      if (lane == 0) flag_store(wflag, (unsigned)(t + 1));
      if (t + 1 < T_) {                          // shadow partA(t+1)
        acc[0] = (f32x4){0,0,0,0}; acc[1] = (f32x4){0,0,0,0};
        acc[2] = (f32x4){0,0,0,0}; acc[3] = (f32x4){0,0,0,0};
        shadow_x(x, t + 1, wv * 16, lane, ldsW, acc);
      }
    }
  } else {
    const int cidx = wg - NGATE;                 // 0..63
    unsigned* wflag = flagH + (size_t)(cidx * 2 + wv) * 16;
    // lane l polls r-gate WG l wave wv (rhq producers, diagonal mt)
    const unsigned* pp1 = flagG + (size_t)(lane * 2 + wv) * 16;
    // lane 0 extra: u-gate WG 64+cidx wave wv (this wave's u rows/cols)
    const unsigned* pe1 = flagG + (size_t)((64 + cidx) * 2 + wv) * 16;
    const bool ae1 = (lane == 0);

    // ---- init h(-1)=h0 (4 rows/lane): regs + h_buf + hq parity-1 frags
    float hreg[4];
#pragma unroll
    for (int r = 0; r < 4; ++r) {
      hreg[r] = h0[(size_t)(r0 + r) * N_ + colg];
      st_f32_sc(h_buf + (size_t)(r0 + r) * N_ + colg, hreg[r]);
      st_bf16_sc(hq + 32768 + frag_off(r0 + r, colg), f2bf(hreg[r]));
    }
    asm volatile("s_waitcnt vmcnt(0)" ::: "memory");
    if (lane == 0) flag_store(wflag, 1u);

    f32x4 acc[4] = {{0,0,0,0},{0,0,0,0},{0,0,0,0},{0,0,0,0}};
    shadow_x(x, 0, wv * 16, lane, ldsW, acc);    // x0 @ Wc_x (shadow)

    for (int t = 0; t < T_; ++t) {
      poll2(pp1, true, pe1, ae1, (unsigned)(t + 1));
      // ---- one issue-batch: 4 u scalars + 32 rhq granules
      float uv[4];
#pragma unroll
      for (int r = 0; r < 4; ++r)
        asm volatile("global_load_dword %0, %1, off sc0 sc1"
                     : "=v"(uv[r])
                     : "v"((unsigned long long)(u_buf + (size_t)(r0 + r) * N_ + colg))
                     : "memory");
      short8v areg[32];
#pragma unroll
      for (int ks = 0; ks < 32; ++ks) {
        const unsigned short* p = rhq + ((size_t)((wv * 32 + ks) * 64 + lane)) * 8;
        asm volatile("global_load_dwordx4 %0, %1, off sc0 sc1"
                     : "=v"(areg[ks]) : "v"((unsigned long long)p) : "memory");
      }
      asm volatile("s_waitcnt vmcnt(0)" ::: "memory");
      __builtin_amdgcn_sched_barrier(0);
#pragma unroll
      for (int ks = 0; ks < 32; ++ks) {
        const int ksg = 32 + ks;                 // rh-part weights
        short8v bhi = *(const short8v*)(ldsW + ((size_t)(0 * 64 + ksg) * 64 + lane) * 8);
        short8v blo = *(const short8v*)(ldsW + ((size_t)(1 * 64 + ksg) * 64 + lane) * 8);
        const int a = (ks & 16) ? 2 : 0;
        acc[a]     = __builtin_amdgcn_mfma_f32_16x16x32_bf16(areg[ks], bhi, acc[a], 0, 0, 0);
        acc[a + 1] = __builtin_amdgcn_mfma_f32_16x16x32_bf16(areg[ks], blo, acc[a + 1], 0, 0, 0);
      }
      // ---- epilogue: merge, tanh, h-update, protocol stores
      f32x4 s4 = (acc[0] + acc[1]) + (acc[2] + acc[3]);
      const float bcol = ldsBias[lane & 15];
      unsigned short* hqw = hq + ((t & 1) << 15);
      float hn[4];
#pragma unroll
      for (int r = 0; r < 4; ++r) {
        float pre = fminf(fmaxf(s4[r] + bcol, -20.f), 20.f);
        const float e = __expf(2.f * pre);
        const float cv = (e - 1.f) / (e + 1.f);  // tanh
        hn[r] = uv[r] * hreg[r] + (1.f - uv[r]) * cv;
        hreg[r] = hn[r];
        st_bf16_sc(hqw + frag_off(r0 + r, colg), f2bf(hn[r]));
        st_f32_sc(h_buf + (size_t)(r0 + r) * N_ + colg, hn[r]);
        out[((size_t)(r0 + r) * T_ + t) * N_ + colg] = hn[r];  // cached; in drain
      }
      asm volatile("s_waitcnt vmcnt(0)" ::: "memory");  // wave-local drain
      if (lane == 0) flag_store(wflag, (unsigned)(t + 2));
      if (t + 1 < T_) {                          // shadow partA(t+1)
        acc[0] = (f32x4){0,0,0,0}; acc[1] = (f32x4){0,0,0,0};
        acc[2] = (f32x4){0,0,0,0}; acc[3] = (f32x4){0,0,0,0};
        shadow_x(x, t + 1, wv * 16, lane, ldsW, acc);
      }
    }
  }
}

extern "C" void kernel_launch(void* const* d_in, const int* in_sizes, int n_in,
                              void* d_out, int out_size, void* d_ws, size_t ws_size,
                              hipStream_t stream) {
  const float* x  = (const float*)d_in[0];
  const float* h0 = (const float*)d_in[1];
  const float* Wg = (const float*)d_in[2];
  const float* bg = (const float*)d_in[3];
  const float* Wc = (const float*)d_in[4];
  const float* bc = (const float*)d_in[5];
  float* out = (float*)d_out;

  char* w = (char*)d_ws;
  unsigned* ctrs       = (unsigned*)(w + 0);             // 384 lines*64B = 24576 (reserve 32768)
  unsigned short* hq   = (unsigned short*)(w + 32768);   // 2 * 65536 (parity)
  unsigned short* rhq  = (unsigned short*)(w + 163840);  // 65536
  float* u_buf         = (float*)(w + 229376);           // 131072
  float* h_buf         = (float*)(w + 360448);           // 131072 -> total 491520 B

  hipFuncSetAttribute((const void*)gru_persistent,
                      hipFuncAttributeMaxDynamicSharedMemorySize, SMEM_BYTES);
  hipMemsetAsync(w, 0, 32768, stream);  // zero flag lines each launch
  gru_persistent<<<NWG, TPB, SMEM_BYTES, stream>>>(
      x, h0, Wg, bg, Wc, bc, out, ctrs, hq, rhq, u_buf, h_buf);
}

// Round 11
// 3206.721 us; speedup vs baseline: 2.4195x; 2.4195x over previous
//
#include <hip/hip_runtime.h>
#include <hip/hip_bf16.h>

#define B_ 32
#define T_ 512
#define D_ 1024
#define N_ 1024
#define NWG 192
#define NGATE 128
#define TPB 256
// LDS: weights 131072 + reduce 2(parity)*8*256*4 = 16384 + bias 64
#define SMEM_BYTES (131072 + 16384 + 64)

typedef __attribute__((ext_vector_type(8))) short short8v;
typedef __attribute__((ext_vector_type(4))) float f32x4;

__device__ __forceinline__ float bf2f(unsigned short u) {
  union { float f; unsigned int i; } c; c.i = ((unsigned int)u) << 16; return c.f;
}
__device__ __forceinline__ unsigned short f2bf(float f) {   // software RNE (scalar)
  union { float f; unsigned int i; } c; c.f = f;
  unsigned int r = c.i + 0x7FFFu + ((c.i >> 16) & 1u);
  return (unsigned short)(r >> 16);
}
// HW packed f32->bf16 RNE (bulk activation conversions)
__device__ __forceinline__ unsigned cvtpk(float a, float b) {
  unsigned r;
  asm("v_cvt_pk_bf16_f32 %0, %1, %2" : "=v"(r) : "v"(a), "v"(b));
  return r;
}
__device__ __forceinline__ short8v pack_frag(f32x4 lo, f32x4 hi) {
  union { unsigned u[4]; short8v s; } c;
  c.u[0] = cvtpk(lo[0], lo[1]); c.u[1] = cvtpk(lo[2], lo[3]);
  c.u[2] = cvtpk(hi[0], hi[1]); c.u[3] = cvtpk(hi[2], hi[3]);
  return c.s;
}

// ---- direct-to-LLC accessors (bypass L1+L2): all cross-WG data.
__device__ __forceinline__ void st_bf16_sc(unsigned short* p, unsigned short v) {
  asm volatile("global_store_short %0, %1, off sc0 sc1"
               :: "v"((unsigned long long)p), "v"((unsigned)v) : "memory");
}
__device__ __forceinline__ void st_f32_sc(float* p, float v) {
  asm volatile("global_store_dword %0, %1, off sc0 sc1"
               :: "v"((unsigned long long)p), "v"(v) : "memory");
}

// ---- per-WAVE epoch flags (single writer per 64B line, monotonic).
// Writer wave: [data sc1 stores] -> wave vmcnt(0) -> lane0 relaxed agent store.
// Reader: relaxed agent poll -> sc1 data loads. (Protocol proven R3/R6-R9.)
__device__ __forceinline__ void flag_store(unsigned* line, unsigned v) {
  __hip_atomic_store(line, v, __ATOMIC_RELAXED, __HIP_MEMORY_SCOPE_AGENT);
}
// Two predicated per-lane poll pointers; lanes with act=false pass trivially.
__device__ __forceinline__ void poll2(const unsigned* p0, bool a0,
                                      const unsigned* p1, bool a1, unsigned tgt) {
  int tries = 0;
  for (;;) {
    unsigned v0 = tgt, v1 = tgt;
    if (a0) v0 = __hip_atomic_load(p0, __ATOMIC_RELAXED, __HIP_MEMORY_SCOPE_AGENT);
    if (a1) v1 = __hip_atomic_load(p1, __ATOMIC_RELAXED, __HIP_MEMORY_SCOPE_AGENT);
    if (__all((int)(v0 >= tgt && v1 >= tgt))) break;
    __builtin_amdgcn_s_sleep(1);
    if (++tries > (1 << 20)) break;   // deadlock valve; never hit normally
  }
}

// Fragment-order flat offset for [32 rows][1024 k] bf16 stored [mt][ks][lane][j].
__device__ __forceinline__ int frag_off(int m, int k) {
  const int mt = m >> 4, ks = k >> 5, kk = k & 31;
  const int l = (m & 15) + (((kk >> 2) & 3) << 4);
  const int j = (kk & 3) + ((kk >> 4) << 2);
  return ((mt * 32 + ks) * 64 + l) * 8 + j;
}

// Build A-fragments for x_t from global f32 (read-only input: plain cached loads).
template <int KS>
__device__ __forceinline__ void build_xfrags(const float* __restrict__ x, int t,
                                             int kbase, int lane,
                                             short8v frag[2][KS]) {
#pragma unroll
  for (int mt = 0; mt < 2; ++mt) {
    const int m = mt * 16 + (lane & 15);
    const float* row = x + ((size_t)m * T_ + t) * D_;
#pragma unroll
    for (int ks = 0; ks < KS; ++ks) {
      const int k0 = kbase + ks * 32 + ((lane >> 4) << 2);
      f32x4 lo = *(const f32x4*)(row + k0);
      f32x4 hi = *(const f32x4*)(row + k0 + 16);
      frag[mt][ks] = pack_frag(lo, hi);
    }
  }
}

// MFMA over KS k-steps, A from registers; B from LDS (frag order, hi/lo split).
template <int KS>
__device__ __forceinline__ void mfma_reg(const short8v frag[2][KS],
                                         const unsigned short* __restrict__ ldsW,
                                         int ksg0, f32x4* acc, int lane) {
#pragma unroll
  for (int mt = 0; mt < 2; ++mt)
#pragma unroll
    for (int ks = 0; ks < KS; ++ks) {
      const int ksg = ksg0 + ks;
      short8v bhi = *(const short8v*)(ldsW + ((size_t)(0 * 64 + ksg) * 64 + lane) * 8);
      short8v blo = *(const short8v*)(ldsW + ((size_t)(1 * 64 + ksg) * 64 + lane) * 8);
      acc[mt] = __builtin_amdgcn_mfma_f32_16x16x32_bf16(frag[mt][ks], bhi, acc[mt], 0, 0, 0);
      acc[mt] = __builtin_amdgcn_mfma_f32_16x16x32_bf16(frag[mt][ks], blo, acc[mt], 0, 0, 0);
    }
}

__global__ __launch_bounds__(TPB, 1) void gru_persistent(
    const float* __restrict__ x, const float* __restrict__ h0,
    const float* __restrict__ Wg, const float* __restrict__ bg,
    const float* __restrict__ Wc, const float* __restrict__ bc,
    float* __restrict__ out,
    unsigned* __restrict__ ctrs,
    unsigned short* __restrict__ hq,     // [2 parity][frag 32x1024] bf16 h
    unsigned short* __restrict__ rhq,    // [frag 32x1024] bf16 r*h
    float* __restrict__ u_buf,           // [32][1024] f32 u gate
    float* __restrict__ h_buf)           // [32][1024] f32 h (row-major)
{
  const int wg = blockIdx.x;
  const int tid = threadIdx.x;
  const int lane = tid & 63;
  const int wv = tid >> 6;

  extern __shared__ char smem[];
  unsigned short* ldsW = (unsigned short*)smem;            // [2][64][64][8]
  float* ldsR = (float*)(smem + 131072);                   // [2 parity][8][256]
  float* ldsBias = (float*)(smem + 131072 + 16384);        // [16]

  unsigned* flagH = ctrs;                  // 256 lines: (cand cidx, wave) epochs
  unsigned* flagG = ctrs + 256 * 16;       // 512 lines: (gate wg, wave) epochs

  const bool is_gate = wg < NGATE;
  const int c0 = (is_gate ? wg : (wg - NGATE)) * 16;
  const float* Wsrc = is_gate ? Wg : Wc;
  const int ldw = is_gate ? 2 * N_ : N_;
  const float* bias = is_gate ? bg : bc;

  const int col = tid & 15, row = tid >> 4;
  const int colg = c0 + col;
  const int b0 = row, b1 = 16 + row;

  // ---- preload weight slice into LDS in MFMA-fragment order, hi/lo split bf16
  for (int i = tid; i < 64 * 64; i += TPB) {
    const int ks = i >> 6, l = i & 63;
    const int n = l & 15, kqp = (l >> 4) * 4;
#pragma unroll
    for (int j = 0; j < 8; ++j) {
      const int k = ks * 32 + ((j < 4) ? 0 : 16) + kqp + (j & 3);
      const float w = Wsrc[(size_t)k * ldw + c0 + n];
      const unsigned short hi = f2bf(w);
      const unsigned short lo = f2bf(w - bf2f(hi));
      ldsW[((size_t)(0 * 64 + ks) * 64 + l) * 8 + j] = hi;
      ldsW[((size_t)(1 * 64 + ks) * 64 + l) * 8 + j] = lo;
    }
  }
  if (tid < 16) ldsBias[tid] = bias[c0 + tid];
  __syncthreads();

  if (is_gate) {
    const bool r_wg = (c0 < N_);
    unsigned* wflag = flagG + (size_t)(wg * 4 + wv) * 16;
    // poll set: 64 lanes -> cand (16wv + lane>>2), wave (lane&3);
    // extra (r-WG, lane 0): cand 'wg' wave 'wv' (the h_buf rows this wave reads)
    const unsigned* pp = flagH + (size_t)((16 * wv + (lane >> 2)) * 4 + (lane & 3)) * 16;
    const unsigned* pe = flagH + (size_t)(wg * 4 + wv) * 16;
    const bool ae = r_wg && (lane == 0);

    f32x4 accA[2] = {{0.f,0.f,0.f,0.f},{0.f,0.f,0.f,0.f}};
    {  // shadow partA(0): x0 @ Wg_x, K=256/wave
      short8v xf[2][8];
      build_xfrags<8>(x, 0, wv * 256, lane, xf);
      mfma_reg<8>(xf, ldsW, wv * 8, accA, lane);
    }
    for (int t = 0; t < T_; ++t) {
      poll2(pp, true, pe, ae, (unsigned)(t + 1));
      // gates read h(t-1): parity buffer (t-1)&1 == (t+1)&1
      const unsigned short* hqr = hq + (((t + 1) & 1) << 15);
      // ---- one issue-batch: (r-WG) 2 h scalars per thread + 16 hq dwordx4
      float hv0 = 0.f, hv1 = 0.f;
      if (r_wg)
        asm volatile("global_load_dword %0, %2, off sc0 sc1\n\t"
                     "global_load_dword %1, %3, off sc0 sc1"
                     : "=&v"(hv0), "=&v"(hv1)
                     : "v"((unsigned long long)(h_buf + b0 * N_ + colg)),
                       "v"((unsigned long long)(h_buf + b1 * N_ + colg))
                     : "memory");
      short8v areg[2][8];
#pragma unroll
      for (int mt = 0; mt < 2; ++mt)
#pragma unroll
        for (int ks = 0; ks < 8; ++ks) {
          const unsigned short* p =
              hqr + ((size_t)((mt * 32 + wv * 8 + ks) * 64 + lane)) * 8;
          asm volatile("global_load_dwordx4 %0, %1, off sc0 sc1"
                       : "=v"(areg[mt][ks]) : "v"((unsigned long long)p) : "memory");
        }
      asm volatile("s_waitcnt vmcnt(0)" ::: "memory");
      __builtin_amdgcn_sched_barrier(0);             // rule #18
#pragma unroll
      for (int mt = 0; mt < 2; ++mt)
#pragma unroll
        for (int ks = 0; ks < 8; ++ks) {
          const int ksg = 32 + wv * 8 + ks;
          short8v bhi = *(const short8v*)(ldsW + ((size_t)(0 * 64 + ksg) * 64 + lane) * 8);
          short8v blo = *(const short8v*)(ldsW + ((size_t)(1 * 64 + ksg) * 64 + lane) * 8);
          accA[mt] = __builtin_amdgcn_mfma_f32_16x16x32_bf16(areg[mt][ks], bhi, accA[mt], 0, 0, 0);
          accA[mt] = __builtin_amdgcn_mfma_f32_16x16x32_bf16(areg[mt][ks], blo, accA[mt], 0, 0, 0);
        }
      float* ldsRp = ldsR + (t & 1) * 2048;          // parity buffer (single sync)
#pragma unroll
      for (int mt = 0; mt < 2; ++mt)
#pragma unroll
        for (int r = 0; r < 4; ++r)
          ldsRp[(wv * 2 + mt) * 256 + (4 * (lane >> 4) + r) * 16 + (lane & 15)] = accA[mt][r];
      __syncthreads();
      {
        float s0 = ldsRp[0 * 256 + tid] + ldsRp[2 * 256 + tid]
                 + ldsRp[4 * 256 + tid] + ldsRp[6 * 256 + tid];
        float s1 = ldsRp[1 * 256 + tid] + ldsRp[3 * 256 + tid]
                 + ldsRp[5 * 256 + tid] + ldsRp[7 * 256 + tid];
        float p0 = fminf(fmaxf(s0 + ldsBias[col], -30.f), 30.f);
        float p1 = fminf(fmaxf(s1 + ldsBias[col], -30.f), 30.f);
        const float g0 = 1.f / (1.f + __expf(-p0));
        const float g1 = 1.f / (1.f + __expf(-p1));
        if (r_wg) {
          st_bf16_sc(rhq + frag_off(b0, colg), f2bf(g0 * hv0));
          st_bf16_sc(rhq + frag_off(b1, colg), f2bf(g1 * hv1));
        } else {
          st_f32_sc(u_buf + b0 * N_ + (colg - N_), g0);
          st_f32_sc(u_buf + b1 * N_ + (colg - N_), g1);
        }
      }
      asm volatile("s_waitcnt vmcnt(0)" ::: "memory");  // wave-local drain
      if (lane == 0) flag_store(wflag, (unsigned)(t + 1));
      if (t + 1 < T_) {                  // shadow: partA(t+1) during cand phase
        accA[0] = (f32x4){0.f,0.f,0.f,0.f};
        accA[1] = (f32x4){0.f,0.f,0.f,0.f};
        short8v xf[2][8];
        build_xfrags<8>(x, t + 1, wv * 256, lane, xf);
        mfma_reg<8>(xf, ldsW, wv * 8, accA, lane);
      }
    }
  } else {
    const int cidx = wg - NGATE;          // 0..63
    unsigned* wflag = flagH + (size_t)(cidx * 4 + wv) * 16;
    // stage-1: 64 lanes -> r-gate (16wv + lane>>2), wave (lane&3);
    //          lanes 0-3 extra -> u-gate (64+cidx), wave lane
    const unsigned* pp1 = flagG + (size_t)((16 * wv + (lane >> 2)) * 4 + (lane & 3)) * 16;
    const unsigned* pe1 = flagG + (size_t)((64 + cidx) * 4 + (lane & 3)) * 16;
    const bool ae1 = (lane < 4);
    // (stage-2 hq write-guard REMOVED: hq is parity double-buffered)

    // ---- init h(-1)=h0 into parity buf 1: regs + h_buf + hq frags; flag = 1
    float hreg0 = h0[b0 * N_ + colg];
    float hreg1 = h0[b1 * N_ + colg];
    st_f32_sc(h_buf + b0 * N_ + colg, hreg0);
    st_f32_sc(h_buf + b1 * N_ + colg, hreg1);
    st_bf16_sc(hq + 32768 + frag_off(b0, colg), f2bf(hreg0));
    st_bf16_sc(hq + 32768 + frag_off(b1, colg), f2bf(hreg1));
    asm volatile("s_waitcnt vmcnt(0)" ::: "memory");
    if (lane == 0) flag_store(wflag, 1u);

    f32x4 accA[2] = {{0.f,0.f,0.f,0.f},{0.f,0.f,0.f,0.f}};
    {  // shadow partA(0): x0 @ Wc_x
      short8v xf[2][8];
      build_xfrags<8>(x, 0, wv * 256, lane, xf);
      mfma_reg<8>(xf, ldsW, wv * 8, accA, lane);
    }
    for (int t = 0; t < T_; ++t) {
      poll2(pp1, true, pe1, ae1, (unsigned)(t + 1));   // rhq slices + my u ready
      float uv0, uv1;
      asm volatile("global_load_dword %0, %2, off sc0 sc1\n\t"
                   "global_load_dword %1, %3, off sc0 sc1"
                   : "=&v"(uv0), "=&v"(uv1)
                   : "v"((unsigned long long)(u_buf + b0 * N_ + colg)),
                     "v"((unsigned long long)(u_buf + b1 * N_ + colg))
                   : "memory");
      short8v areg[2][8];
#pragma unroll
      for (int mt = 0; mt < 2; ++mt)
#pragma unroll
        for (int ks = 0; ks < 8; ++ks) {
          const unsigned short* p =
              rhq + ((size_t)((mt * 32 + wv * 8 + ks) * 64 + lane)) * 8;
          asm volatile("global_load_dwordx4 %0, %1, off sc0 sc1"
                       : "=v"(areg[mt][ks]) : "v"((unsigned long long)p) : "memory");
        }
      asm volatile("s_waitcnt vmcnt(0)" ::: "memory");
      __builtin_amdgcn_sched_barrier(0);
#pragma unroll
      for (int mt = 0; mt < 2; ++mt)
#pragma unroll
        for (int ks = 0; ks < 8; ++ks) {
          const int ksg = 32 + wv * 8 + ks;
          short8v bhi = *(const short8v*)(ldsW + ((size_t)(0 * 64 + ksg) * 64 + lane) * 8);
          short8v blo = *(const short8v*)(ldsW + ((size_t)(1 * 64 + ksg) * 64 + lane) * 8);
          accA[mt] = __builtin_amdgcn_mfma_f32_16x16x32_bf16(areg[mt][ks], bhi, accA[mt], 0, 0, 0);
          accA[mt] = __builtin_amdgcn_mfma_f32_16x16x32_bf16(areg[mt][ks], blo, accA[mt], 0, 0, 0);
        }
      float* ldsRp = ldsR + (t & 1) * 2048;
#pragma unroll
      for (int mt = 0; mt < 2; ++mt)
#pragma unroll
        for (int r = 0; r < 4; ++r)
          ldsRp[(wv * 2 + mt) * 256 + (4 * (lane >> 4) + r) * 16 + (lane & 15)] = accA[mt][r];
      __syncthreads();
      {
        float s0 = ldsRp[0 * 256 + tid] + ldsRp[2 * 256 + tid]
                 + ldsRp[4 * 256 + tid] + ldsRp[6 * 256 + tid];
        float s1 = ldsRp[1 * 256 + tid] + ldsRp[3 * 256 + tid]
                 + ldsRp[5 * 256 + tid] + ldsRp[7 * 256 + tid];
        float p0 = fminf(fmaxf(s0 + ldsBias[col], -20.f), 20.f);
        float p1v = fminf(fmaxf(s1 + ldsBias[col], -20.f), 20.f);
        const float e0 = __expf(2.f * p0), e1 = __expf(2.f * p1v);
        const float c0v = (e0 - 1.f) / (e0 + 1.f);   // tanh
        const float c1v = (e1 - 1.f) / (e1 + 1.f);
        const float hn0 = uv0 * hreg0 + (1.f - uv0) * c0v;
        const float hn1 = uv1 * hreg1 + (1.f - uv1) * c1v;
        hreg0 = hn0; hreg1 = hn1;
        unsigned short* hqw = hq + ((t & 1) << 15);  // h(t) -> parity buf t&1
        st_bf16_sc(hqw + frag_off(b0, colg), f2bf(hn0));
        st_bf16_sc(hqw + frag_off(b1, colg), f2bf(hn1));
        st_f32_sc(h_buf + b0 * N_ + colg, hn0);
        st_f32_sc(h_buf + b1 * N_ + colg, hn1);
        out[((size_t)b0 * T_ + t) * N_ + colg] = hn0;   // cached; shares the drain
        out[((size_t)b1 * T_ + t) * N_ + colg] = hn1;
      }
      asm volatile("s_waitcnt vmcnt(0)" ::: "memory");  // wave-local drain
      if (lane == 0) flag_store(wflag, (unsigned)(t + 2));
      if (t + 1 < T_) {                  // shadow: partA(t+1) during gate phase
        accA[0] = (f32x4){0.f,0.f,0.f,0.f};
        accA[1] = (f32x4){0.f,0.f,0.f,0.f};
        short8v xf[2][8];
        build_xfrags<8>(x, t + 1, wv * 256, lane, xf);
        mfma_reg<8>(xf, ldsW, wv * 8, accA, lane);
      }
    }
  }
}

extern "C" void kernel_launch(void* const* d_in, const int* in_sizes, int n_in,
                              void* d_out, int out_size, void* d_ws, size_t ws_size,
                              hipStream_t stream) {
  const float* x  = (const float*)d_in[0];
  const float* h0 = (const float*)d_in[1];
  const float* Wg = (const float*)d_in[2];
  const float* bg = (const float*)d_in[3];
  const float* Wc = (const float*)d_in[4];
  const float* bc = (const float*)d_in[5];
  float* out = (float*)d_out;

  char* w = (char*)d_ws;
  unsigned* ctrs       = (unsigned*)(w + 0);             // 768 lines * 64B = 49152
  unsigned short* hq   = (unsigned short*)(w + 49152);   // 2 * 65536 (parity)
  unsigned short* rhq  = (unsigned short*)(w + 180224);  // 65536
  float* u_buf         = (float*)(w + 245760);           // 131072
  float* h_buf         = (float*)(w + 376832);           // 131072 -> total 507904 B

  hipFuncSetAttribute((const void*)gru_persistent,
                      hipFuncAttributeMaxDynamicSharedMemorySize, SMEM_BYTES);
  hipMemsetAsync(w, 0, 49152, stream);  // zero flag lines each launch
  gru_persistent<<<NWG, TPB, SMEM_BYTES, stream>>>(
      x, h0, Wg, bg, Wc, bc, out, ctrs, hq, rhq, u_buf, h_buf);
}

// Round 17
// 3162.437 us; speedup vs baseline: 2.4534x; 1.0140x over previous
//
#include <hip/hip_runtime.h>
#include <hip/hip_bf16.h>

#define B_ 32
#define T_ 512
#define D_ 1024
#define N_ 1024
#define NWG 192
#define NGATE 128
#define TPB 256
// LDS: weights 131072 + reduce 2(parity)*8*256*4 = 16384 + bias 64
#define SMEM_BYTES (131072 + 16384 + 64)

typedef __attribute__((ext_vector_type(8))) short short8v;
typedef __attribute__((ext_vector_type(4))) float f32x4;

__device__ __forceinline__ float bf2f(unsigned short u) {
  union { float f; unsigned int i; } c; c.i = ((unsigned int)u) << 16; return c.f;
}
__device__ __forceinline__ unsigned short f2bf(float f) {   // software RNE (scalar)
  union { float f; unsigned int i; } c; c.f = f;
  unsigned int r = c.i + 0x7FFFu + ((c.i >> 16) & 1u);
  return (unsigned short)(r >> 16);
}
// HW packed f32->bf16 RNE (bulk activation conversions)
__device__ __forceinline__ unsigned cvtpk(float a, float b) {
  unsigned r;
  asm("v_cvt_pk_bf16_f32 %0, %1, %2" : "=v"(r) : "v"(a), "v"(b));
  return r;
}
__device__ __forceinline__ short8v pack_frag(f32x4 lo, f32x4 hi) {
  union { unsigned u[4]; short8v s; } c;
  c.u[0] = cvtpk(lo[0], lo[1]); c.u[1] = cvtpk(lo[2], lo[3]);
  c.u[2] = cvtpk(hi[0], hi[1]); c.u[3] = cvtpk(hi[2], hi[3]);
  return c.s;
}

// ---- direct-to-LLC accessors (bypass L1+L2): all cross-WG data.
__device__ __forceinline__ void st_bf16_sc(unsigned short* p, unsigned short v) {
  asm volatile("global_store_short %0, %1, off sc0 sc1"
               :: "v"((unsigned long long)p), "v"((unsigned)v) : "memory");
}
__device__ __forceinline__ void st_f32_sc(float* p, float v) {
  asm volatile("global_store_dword %0, %1, off sc0 sc1"
               :: "v"((unsigned long long)p), "v"(v) : "memory");
}

// ---- per-WAVE epoch flags (single writer per 64B line, monotonic).
// Writer wave: [data sc1 stores] -> wave vmcnt(0) -> lane0 relaxed agent store.
// Reader: relaxed agent poll -> sc1 data loads. (Protocol proven R3/R6-R11.)
__device__ __forceinline__ void flag_store(unsigned* line, unsigned v) {
  __hip_atomic_store(line, v, __ATOMIC_RELAXED, __HIP_MEMORY_SCOPE_AGENT);
}
// Two predicated per-lane poll pointers; lanes with act=false pass trivially.
__device__ __forceinline__ void poll2(const unsigned* p0, bool a0,
                                      const unsigned* p1, bool a1, unsigned tgt) {
  int tries = 0;
  for (;;) {
    unsigned v0 = tgt, v1 = tgt;
    if (a0) v0 = __hip_atomic_load(p0, __ATOMIC_RELAXED, __HIP_MEMORY_SCOPE_AGENT);
    if (a1) v1 = __hip_atomic_load(p1, __ATOMIC_RELAXED, __HIP_MEMORY_SCOPE_AGENT);
    if (__all((int)(v0 >= tgt && v1 >= tgt))) break;
    __builtin_amdgcn_s_sleep(1);
    if (++tries > (1 << 20)) break;   // deadlock valve; never hit normally
  }
}

// Fragment-order flat offset for [32 rows][1024 k] bf16 stored [mt][ks][lane][j].
__device__ __forceinline__ int frag_off(int m, int k) {
  const int mt = m >> 4, ks = k >> 5, kk = k & 31;
  const int l = (m & 15) + (((kk >> 2) & 3) << 4);
  const int j = (kk & 3) + ((kk >> 4) << 2);
  return ((mt * 32 + ks) * 64 + l) * 8 + j;
}

// Build A-fragments for x_t from global f32 (read-only input: plain cached loads).
template <int KS>
__device__ __forceinline__ void build_xfrags(const float* __restrict__ x, int t,
                                             int kbase, int lane,
                                             short8v frag[2][KS]) {
#pragma unroll
  for (int mt = 0; mt < 2; ++mt) {
    const int m = mt * 16 + (lane & 15);
    const float* row = x + ((size_t)m * T_ + t) * D_;
#pragma unroll
    for (int ks = 0; ks < KS; ++ks) {
      const int k0 = kbase + ks * 32 + ((lane >> 4) << 2);
      f32x4 lo = *(const f32x4*)(row + k0);
      f32x4 hi = *(const f32x4*)(row + k0 + 16);
      frag[mt][ks] = pack_frag(lo, hi);
    }
  }
}

// MFMA over KS k-steps, A from registers; B from LDS (frag order, hi/lo split).
template <int KS>
__device__ __forceinline__ void mfma_reg(const short8v frag[2][KS],
                                         const unsigned short* __restrict__ ldsW,
                                         int ksg0, f32x4* acc, int lane) {
#pragma unroll
  for (int mt = 0; mt < 2; ++mt)
#pragma unroll
    for (int ks = 0; ks < KS; ++ks) {
      const int ksg = ksg0 + ks;
      short8v bhi = *(const short8v*)(ldsW + ((size_t)(0 * 64 + ksg) * 64 + lane) * 8);
      short8v blo = *(const short8v*)(ldsW + ((size_t)(1 * 64 + ksg) * 64 + lane) * 8);
      acc[mt] = __builtin_amdgcn_mfma_f32_16x16x32_bf16(frag[mt][ks], bhi, acc[mt], 0, 0, 0);
      acc[mt] = __builtin_amdgcn_mfma_f32_16x16x32_bf16(frag[mt][ks], blo, acc[mt], 0, 0, 0);
    }
}

__global__ __launch_bounds__(TPB, 1) void gru_persistent(
    const float* __restrict__ x, const float* __restrict__ h0,
    const float* __restrict__ Wg, const float* __restrict__ bg,
    const float* __restrict__ Wc, const float* __restrict__ bc,
    float* __restrict__ out,
    unsigned* __restrict__ ctrs,
    unsigned short* __restrict__ hq,     // [2 parity][frag 32x1024] bf16 h
    unsigned short* __restrict__ rhq,    // [frag 32x1024] bf16 r*h
    float* __restrict__ u_buf,           // [32][1024] f32 u gate
    float* __restrict__ h_buf)           // [32][1024] f32 h (row-major)
{
  const int wg = blockIdx.x;
  const int tid = threadIdx.x;
  const int lane = tid & 63;
  const int wv = tid >> 6;

  extern __shared__ char smem[];
  unsigned short* ldsW = (unsigned short*)smem;            // [2][64][64][8]
  float* ldsR = (float*)(smem + 131072);                   // [2 parity][8][256]
  float* ldsBias = (float*)(smem + 131072 + 16384);        // [16]

  unsigned* flagH = ctrs;                  // 256 lines: (cand cidx, wave) epochs
  unsigned* flagG = ctrs + 256 * 16;       // 512 lines: (gate wg, wave) epochs

  const bool is_gate = wg < NGATE;
  const int c0 = (is_gate ? wg : (wg - NGATE)) * 16;
  const float* Wsrc = is_gate ? Wg : Wc;
  const int ldw = is_gate ? 2 * N_ : N_;
  const float* bias = is_gate ? bg : bc;

  const int col = tid & 15, row = tid >> 4;
  const int colg = c0 + col;
  const int b0 = row, b1 = 16 + row;

  // ---- preload weight slice into LDS in MFMA-fragment order, hi/lo split bf16
  for (int i = tid; i < 64 * 64; i += TPB) {
    const int ks = i >> 6, l = i & 63;
    const int n = l & 15, kqp = (l >> 4) * 4;
#pragma unroll
    for (int j = 0; j < 8; ++j) {
      const int k = ks * 32 + ((j < 4) ? 0 : 16) + kqp + (j & 3);
      const float w = Wsrc[(size_t)k * ldw + c0 + n];
      const unsigned short hi = f2bf(w);
      const unsigned short lo = f2bf(w - bf2f(hi));
      ldsW[((size_t)(0 * 64 + ks) * 64 + l) * 8 + j] = hi;
      ldsW[((size_t)(1 * 64 + ks) * 64 + l) * 8 + j] = lo;
    }
  }
  if (tid < 16) ldsBias[tid] = bias[c0 + tid];
  __syncthreads();

  if (is_gate) {
    const bool r_wg = (c0 < N_);
    unsigned* wflag = flagG + (size_t)(wg * 4 + wv) * 16;
    // poll set: 64 lanes -> cand (16wv + lane>>2), wave (lane&3);
    // extra (r-WG, lane 0): cand 'wg' wave 'wv' (the h_buf rows this wave reads)
    const unsigned* pp = flagH + (size_t)((16 * wv + (lane >> 2)) * 4 + (lane & 3)) * 16;
    const unsigned* pe = flagH + (size_t)(wg * 4 + wv) * 16;
    const bool ae = r_wg && (lane == 0);

    f32x4 accA[2] = {{0.f,0.f,0.f,0.f},{0.f,0.f,0.f,0.f}};
    {  // shadow partA(0): x0 @ Wg_x, K=256/wave
      short8v xf[2][8];
      build_xfrags<8>(x, 0, wv * 256, lane, xf);
      mfma_reg<8>(xf, ldsW, wv * 8, accA, lane);
    }
    for (int t = 0; t < T_; ++t) {
      poll2(pp, true, pe, ae, (unsigned)(t + 1));
      // gates read h(t-1): parity buffer (t-1)&1 == (t+1)&1
      const unsigned short* hqr = hq + (((t + 1) & 1) << 15);
      // ---- one issue-batch: (r-WG) 2 h scalars per thread + 16 hq dwordx4
      float hv0 = 0.f, hv1 = 0.f;
      if (r_wg)
        asm volatile("global_load_dword %0, %2, off sc0 sc1\n\t"
                     "global_load_dword %1, %3, off sc0 sc1"
                     : "=&v"(hv0), "=&v"(hv1)
                     : "v"((unsigned long long)(h_buf + b0 * N_ + colg)),
                       "v"((unsigned long long)(h_buf + b1 * N_ + colg))
                     : "memory");
      short8v areg[2][8];
#pragma unroll
      for (int mt = 0; mt < 2; ++mt)
#pragma unroll
        for (int ks = 0; ks < 8; ++ks) {
          const unsigned short* p =
              hqr + ((size_t)((mt * 32 + wv * 8 + ks) * 64 + lane)) * 8;
          asm volatile("global_load_dwordx4 %0, %1, off sc0 sc1"
                       : "=v"(areg[mt][ks]) : "v"((unsigned long long)p) : "memory");
        }
      asm volatile("s_waitcnt vmcnt(0)" ::: "memory");
      __builtin_amdgcn_sched_barrier(0);             // rule #18
#pragma unroll
      for (int mt = 0; mt < 2; ++mt)
#pragma unroll
        for (int ks = 0; ks < 8; ++ks) {
          const int ksg = 32 + wv * 8 + ks;
          short8v bhi = *(const short8v*)(ldsW + ((size_t)(0 * 64 + ksg) * 64 + lane) * 8);
          short8v blo = *(const short8v*)(ldsW + ((size_t)(1 * 64 + ksg) * 64 + lane) * 8);
          accA[mt] = __builtin_amdgcn_mfma_f32_16x16x32_bf16(areg[mt][ks], bhi, accA[mt], 0, 0, 0);
          accA[mt] = __builtin_amdgcn_mfma_f32_16x16x32_bf16(areg[mt][ks], blo, accA[mt], 0, 0, 0);
        }
      float* ldsRp = ldsR + (t & 1) * 2048;          // parity buffer (single sync)
#pragma unroll
      for (int mt = 0; mt < 2; ++mt)
#pragma unroll
        for (int r = 0; r < 4; ++r)
          ldsRp[(wv * 2 + mt) * 256 + (4 * (lane >> 4) + r) * 16 + (lane & 15)] = accA[mt][r];
      __syncthreads();
      {
        float s0 = ldsRp[0 * 256 + tid] + ldsRp[2 * 256 + tid]
                 + ldsRp[4 * 256 + tid] + ldsRp[6 * 256 + tid];
        float s1 = ldsRp[1 * 256 + tid] + ldsRp[3 * 256 + tid]
                 + ldsRp[5 * 256 + tid] + ldsRp[7 * 256 + tid];
        float p0 = fminf(fmaxf(s0 + ldsBias[col], -30.f), 30.f);
        float p1 = fminf(fmaxf(s1 + ldsBias[col], -30.f), 30.f);
        const float g0 = 1.f / (1.f + __expf(-p0));
        const float g1 = 1.f / (1.f + __expf(-p1));
        if (r_wg) {
          st_bf16_sc(rhq + frag_off(b0, colg), f2bf(g0 * hv0));
          st_bf16_sc(rhq + frag_off(b1, colg), f2bf(g1 * hv1));
        } else {
          st_f32_sc(u_buf + b0 * N_ + (colg - N_), g0);
          st_f32_sc(u_buf + b1 * N_ + (colg - N_), g1);
        }
      }
      asm volatile("s_waitcnt vmcnt(0)" ::: "memory");  // wave-local drain
      if (lane == 0) flag_store(wflag, (unsigned)(t + 1));
      if (t + 1 < T_) {                  // shadow: partA(t+1) during cand phase
        accA[0] = (f32x4){0.f,0.f,0.f,0.f};
        accA[1] = (f32x4){0.f,0.f,0.f,0.f};
        short8v xf[2][8];
        build_xfrags<8>(x, t + 1, wv * 256, lane, xf);
        mfma_reg<8>(xf, ldsW, wv * 8, accA, lane);
      }
    }
  } else {
    const int cidx = wg - NGATE;          // 0..63
    unsigned* wflag = flagH + (size_t)(cidx * 4 + wv) * 16;
    // stage-1: 64 lanes -> r-gate (16wv + lane>>2), wave (lane&3);
    //          lanes 0-3 extra -> u-gate (64+cidx), wave lane
    const unsigned* pp1 = flagG + (size_t)((16 * wv + (lane >> 2)) * 4 + (lane & 3)) * 16;
    const unsigned* pe1 = flagG + (size_t)((64 + cidx) * 4 + (lane & 3)) * 16;
    const bool ae1 = (lane < 4);
    // (stage-2 hq write-guard REMOVED: hq is parity double-buffered)

    // ---- init h(-1)=h0 into parity buf 1: regs + h_buf + hq frags; flag = 1
    float hreg0 = h0[b0 * N_ + colg];
    float hreg1 = h0[b1 * N_ + colg];
    st_f32_sc(h_buf + b0 * N_ + colg, hreg0);
    st_f32_sc(h_buf + b1 * N_ + colg, hreg1);
    st_bf16_sc(hq + 32768 + frag_off(b0, colg), f2bf(hreg0));
    st_bf16_sc(hq + 32768 + frag_off(b1, colg), f2bf(hreg1));
    asm volatile("s_waitcnt vmcnt(0)" ::: "memory");
    if (lane == 0) flag_store(wflag, 1u);

    f32x4 accA[2] = {{0.f,0.f,0.f,0.f},{0.f,0.f,0.f,0.f}};
    {  // shadow partA(0): x0 @ Wc_x
      short8v xf[2][8];
      build_xfrags<8>(x, 0, wv * 256, lane, xf);
      mfma_reg<8>(xf, ldsW, wv * 8, accA, lane);
    }
    for (int t = 0; t < T_; ++t) {
      poll2(pp1, true, pe1, ae1, (unsigned)(t + 1));   // rhq slices + my u ready
      float uv0, uv1;
      asm volatile("global_load_dword %0, %2, off sc0 sc1\n\t"
                   "global_load_dword %1, %3, off sc0 sc1"
                   : "=&v"(uv0), "=&v"(uv1)
                   : "v"((unsigned long long)(u_buf + b0 * N_ + colg)),
                     "v"((unsigned long long)(u_buf + b1 * N_ + colg))
                   : "memory");
      short8v areg[2][8];
#pragma unroll
      for (int mt = 0; mt < 2; ++mt)
#pragma unroll
        for (int ks = 0; ks < 8; ++ks) {
          const unsigned short* p =
              rhq + ((size_t)((mt * 32 + wv * 8 + ks) * 64 + lane)) * 8;
          asm volatile("global_load_dwordx4 %0, %1, off sc0 sc1"
                       : "=v"(areg[mt][ks]) : "v"((unsigned long long)p) : "memory");
        }
      asm volatile("s_waitcnt vmcnt(0)" ::: "memory");
      __builtin_amdgcn_sched_barrier(0);
#pragma unroll
      for (int mt = 0; mt < 2; ++mt)
#pragma unroll
        for (int ks = 0; ks < 8; ++ks) {
          const int ksg = 32 + wv * 8 + ks;
          short8v bhi = *(const short8v*)(ldsW + ((size_t)(0 * 64 + ksg) * 64 + lane) * 8);
          short8v blo = *(const short8v*)(ldsW + ((size_t)(1 * 64 + ksg) * 64 + lane) * 8);
          accA[mt] = __builtin_amdgcn_mfma_f32_16x16x32_bf16(areg[mt][ks], bhi, accA[mt], 0, 0, 0);
          accA[mt] = __builtin_amdgcn_mfma_f32_16x16x32_bf16(areg[mt][ks], blo, accA[mt], 0, 0, 0);
        }
      float* ldsRp = ldsR + (t & 1) * 2048;
#pragma unroll
      for (int mt = 0; mt < 2; ++mt)
#pragma unroll
        for (int r = 0; r < 4; ++r)
          ldsRp[(wv * 2 + mt) * 256 + (4 * (lane >> 4) + r) * 16 + (lane & 15)] = accA[mt][r];
      __syncthreads();
      {
        float s0 = ldsRp[0 * 256 + tid] + ldsRp[2 * 256 + tid]
                 + ldsRp[4 * 256 + tid] + ldsRp[6 * 256 + tid];
        float s1 = ldsRp[1 * 256 + tid] + ldsRp[3 * 256 + tid]
                 + ldsRp[5 * 256 + tid] + ldsRp[7 * 256 + tid];
        float p0 = fminf(fmaxf(s0 + ldsBias[col], -20.f), 20.f);
        float p1v = fminf(fmaxf(s1 + ldsBias[col], -20.f), 20.f);
        const float e0 = __expf(2.f * p0), e1 = __expf(2.f * p1v);
        const float c0v = (e0 - 1.f) / (e0 + 1.f);   // tanh
        const float c1v = (e1 - 1.f) / (e1 + 1.f);
        const float hn0 = uv0 * hreg0 + (1.f - uv0) * c0v;
        const float hn1 = uv1 * hreg1 + (1.f - uv1) * c1v;
        hreg0 = hn0; hreg1 = hn1;
        unsigned short* hqw = hq + ((t & 1) << 15);  // h(t) -> parity buf t&1
        st_bf16_sc(hqw + frag_off(b0, colg), f2bf(hn0));
        st_bf16_sc(hqw + frag_off(b1, colg), f2bf(hn1));
        st_f32_sc(h_buf + b0 * N_ + colg, hn0);
        st_f32_sc(h_buf + b1 * N_ + colg, hn1);
        out[((size_t)b0 * T_ + t) * N_ + colg] = hn0;   // cached; shares the drain
        out[((size_t)b1 * T_ + t) * N_ + colg] = hn1;
      }
      asm volatile("s_waitcnt vmcnt(0)" ::: "memory");  // wave-local drain
      if (lane == 0) flag_store(wflag, (unsigned)(t + 2));
      if (t + 1 < T_) {                  // shadow: partA(t+1) during gate phase
        accA[0] = (f32x4){0.f,0.f,0.f,0.f};
        accA[1] = (f32x4){0.f,0.f,0.f,0.f};
        short8v xf[2][8];
        build_xfrags<8>(x, t + 1, wv * 256, lane, xf);
        mfma_reg<8>(xf, ldsW, wv * 8, accA, lane);
      }
    }
  }
}

extern "C" void kernel_launch(void* const* d_in, const int* in_sizes, int n_in,
                              void* d_out, int out_size, void* d_ws, size_t ws_size,
                              hipStream_t stream) {
  const float* x  = (const float*)d_in[0];
  const float* h0 = (const float*)d_in[1];
  const float* Wg = (const float*)d_in[2];
  const float* bg = (const float*)d_in[3];
  const float* Wc = (const float*)d_in[4];
  const float* bc = (const float*)d_in[5];
  float* out = (float*)d_out;

  char* w = (char*)d_ws;
  unsigned* ctrs       = (unsigned*)(w + 0);             // 768 lines * 64B = 49152
  unsigned short* hq   = (unsigned short*)(w + 49152);   // 2 * 65536 (parity)
  unsigned short* rhq  = (unsigned short*)(w + 180224);  // 65536
  float* u_buf         = (float*)(w + 245760);           // 131072
  float* h_buf         = (float*)(w + 376832);           // 131072 -> total 507904 B

  hipFuncSetAttribute((const void*)gru_persistent,
                      hipFuncAttributeMaxDynamicSharedMemorySize, SMEM_BYTES);
  hipMemsetAsync(w, 0, 49152, stream);  // zero flag lines each launch
  gru_persistent<<<NWG, TPB, SMEM_BYTES, stream>>>(
      x, h0, Wg, bg, Wc, bc, out, ctrs, hq, rhq, u_buf, h_buf);
}